// Round 2
// baseline (487.956 us; speedup 1.0000x reference)
//
#include <hip/hip_runtime.h>

#define BT 16
#define NN 8192
#define FIN 128
#define FOUT 32
#define NB 512       // BT*FOUT
#define SPLITK 4
#define KSPAN (NN / SPLITK)   // 2048
#define BKK 64
#define PADK 72      // As row stride: 144 B -> conflict-free in 8-lane groups

typedef __attribute__((ext_vector_type(8))) short short8;
typedef __attribute__((ext_vector_type(4))) float float4v;

__device__ __forceinline__ float bf2f(unsigned short u) {
    unsigned v = ((unsigned)u) << 16;
    float f;
    __builtin_memcpy(&f, &v, 4);
    return f;
}
__device__ __forceinline__ unsigned short f2bf(float f) {
    unsigned u;
    __builtin_memcpy(&u, &f, 4);
    u += 0x7FFFu + ((u >> 16) & 1u);   // RNE
    return (unsigned short)(u >> 16);
}

// async global->LDS, 16 B per lane; LDS dest = wave-uniform base + lane*16
__device__ __forceinline__ void load_lds16(const unsigned short* g, unsigned short* l) {
    __builtin_amdgcn_global_load_lds((const __attribute__((address_space(1))) void*)g,
                                     (__attribute__((address_space(3))) void*)l, 16, 0, 0);
}

// ---------------------------------------------------------------------------
// Sniff bf16-vs-fp32 (proven R1/R2) + zero sumh[512].
// ---------------------------------------------------------------------------
__global__ void sniff_dtype(const unsigned* __restrict__ Wraw, unsigned* __restrict__ flag,
                            float* __restrict__ sumh) {
    int lane = threadIdx.x;
    unsigned u = Wraw[lane];
    float f = bf2f((unsigned short)(u & 0xFFFFu));
    float af = fabsf(f);
    bool plaus = (af > 1e-5f) && (af < 1e3f);
    unsigned long long msk = __ballot(plaus);
    if (lane == 0) flag[0] = (__popcll(msk) >= 32) ? 1u : 0u;
#pragma unroll
    for (int r = 0; r < 8; ++r) sumh[lane + 64 * r] = 0.f;
}

// ---------------------------------------------------------------------------
// K1: [0,128) zero s2 | [128,1152) h = inp @ W  (+ per-bt column sums of h)
// ---------------------------------------------------------------------------
__launch_bounds__(256)
__global__ void k1(const void* __restrict__ inp_raw, const void* __restrict__ W_raw,
                   unsigned short* __restrict__ Ht, float* __restrict__ sumh,
                   float4* __restrict__ s2v, const unsigned* __restrict__ flagp) {
    __shared__ __align__(16) unsigned short Wt[32 * 136];
    int bid = blockIdx.x;
    const int tid = threadIdx.x;

    if (bid < 128) {                 // ---- zero s2 (131072 floats = 32768 float4)
        float4 z; z.x = z.y = z.z = z.w = 0.f;
        s2v[bid * 256 + tid] = z;
        return;
    }
    bid -= 128;                      // ---- h-part (R2 k1 body, proven)
    const int bt = bid >> 6;
    const int j0 = (bid & 63) * 128;
    const bool isbf = (*flagp != 0u);

    if (isbf) {
        const unsigned short* Wb = (const unsigned short*)W_raw;
#pragma unroll
        for (int r = 0; r < 16; ++r) {
            int idx = tid + 256 * r, i = idx >> 5, o = idx & 31;
            Wt[o * 136 + i] = Wb[idx];
        }
    } else {
        const float* Wf = (const float*)W_raw;
#pragma unroll
        for (int r = 0; r < 16; ++r) {
            int idx = tid + 256 * r, i = idx >> 5, o = idx & 31;
            Wt[o * 136 + i] = f2bf(Wf[idx]);
        }
    }
    __syncthreads();

    const int lane = tid & 63, w = tid >> 6;
    const int m = lane & 15, q = lane >> 4;
    const int mt = (w & 1) * 16;
    const int nt = (w >> 1) * 64;

    float4v acc[4];
#pragma unroll
    for (int c = 0; c < 4; ++c) { float4v z = {0.f, 0.f, 0.f, 0.f}; acc[c] = z; }

#pragma unroll
    for (int kstep = 0; kstep < 4; ++kstep) {
        short8 af = *(const short8*)&Wt[(mt + m) * 136 + kstep * 32 + q * 8];
#pragma unroll
        for (int c = 0; c < 4; ++c) {
            int j = j0 + nt + c * 16 + m;
            short8 bfrag;
            if (isbf) {
                bfrag = *(const short8*)((const unsigned short*)inp_raw +
                        ((size_t)bt * NN + j) * FIN + kstep * 32 + q * 8);
            } else {
                const float* fp = (const float*)inp_raw + ((size_t)bt * NN + j) * FIN + kstep * 32 + q * 8;
                float4 f0 = *(const float4*)fp;
                float4 f1 = *(const float4*)(fp + 4);
                union { unsigned short u[8]; short8 v; } t;
                t.u[0] = f2bf(f0.x); t.u[1] = f2bf(f0.y); t.u[2] = f2bf(f0.z); t.u[3] = f2bf(f0.w);
                t.u[4] = f2bf(f1.x); t.u[5] = f2bf(f1.y); t.u[6] = f2bf(f1.z); t.u[7] = f2bf(f1.w);
                bfrag = t.v;
            }
            acc[c] = __builtin_amdgcn_mfma_f32_16x16x32_bf16(af, bfrag, acc[c], 0, 0, 0);
        }
    }

#pragma unroll
    for (int c = 0; c < 4; ++c) {
#pragma unroll
        for (int e = 0; e < 4; ++e) {
            int o = mt + q * 4 + e;
            int j = j0 + nt + c * 16 + m;
            Ht[(size_t)(bt * FOUT + o) * NN + j] = f2bf(acc[c][e]);
        }
    }
#pragma unroll
    for (int e = 0; e < 4; ++e) {
        float s = acc[0][e] + acc[1][e] + acc[2][e] + acc[3][e];
        s += __shfl_xor(s, 1); s += __shfl_xor(s, 2);
        s += __shfl_xor(s, 4); s += __shfl_xor(s, 8);
        if (m == 0) atomicAdd(&sumh[bt * FOUT + mt + q * 4 + e], s);
    }
}

// ---------------------------------------------------------------------------
// K2 fused: s2[bt][i] += sum_o a2[i,o] * (sum_k (adj[k][i]>0) * Ht[bt*32+o][k])
// Tile: 64(i) x 512(all n) x BK=64, split-K=4 -> 512 blocks, 8 waves, 2/CU.
// adj read ONCE chip-wide. Register-slimmed for the 128-VGPR cap of
// __launch_bounds__(512,4): no cross-step prefetch array (useless anyway —
// every __syncthreads drains vmcnt(0)), DMA source offsets recomputed per
// step, int32 address math. adj loads issued BEFORE the B DMA so the
// convert's vmcnt wait covers only them.
// ---------------------------------------------------------------------------
__launch_bounds__(512, 4)
__global__ void k2_fused(const int* __restrict__ adj, const unsigned short* __restrict__ Ht,
                         const void* __restrict__ a_raw, float* __restrict__ s2,
                         const unsigned* __restrict__ flagp) {
    __shared__ __align__(16) unsigned short As[64 * PADK];   // 9.2 KB
    __shared__ __align__(16) unsigned short Bs[512 * 64];    // 64 KB
    const int tid = threadIdx.x;
    const int lane = tid & 63;
    const int w = tid >> 6;              // wave 0..7, owns n in [w*64, w*64+64)
    const int m = lane & 15, q = lane >> 4;
    const int wn = w * 64;

    // XCD-aware decomposition: bid&7 ~ XCD; 2 XCDs per z-slice -> each XCD's
    // 2 MB Ht k-slice stays resident in its private L2.
    const int bid = blockIdx.x;
    const int xcd = bid & 7;
    const int z = xcd >> 1;                          // 0..3
    const int ib = (bid >> 3) | ((xcd & 1) << 6);    // 0..127 (bijective)
    const int i0 = ib * 64;
    const int zbase = z * KSPAN;

    // A staging: this thread covers column i = i0+lane, k-octet kh = w.
    // dword offsets stay < 67M -> int32 math.
    const int* gcol = adj + (zbase + w * 8) * NN + i0 + lane;

    float4v acc[4][4];
#pragma unroll
    for (int r = 0; r < 4; ++r)
#pragma unroll
        for (int c = 0; c < 4; ++c) { float4v zz = {0.f, 0.f, 0.f, 0.f}; acc[r][c] = zz; }

    for (int ks0 = 0; ks0 < KSPAN; ks0 += BKK) {
        const int k0 = zbase + ks0;
        __syncthreads();                      // prev compute done; LDS writable
        // ---- adj loads first (HBM, longest latency); die at the convert
        int av[8];
#pragma unroll
        for (int kk = 0; kk < 8; ++kk)
            av[kk] = gcol[(ks0 + kk) * NN];
        // ---- B: 8 DMA calls/wave, source offsets recomputed (saves VGPRs)
#pragma unroll
        for (int c = 0; c < 8; ++c) {
            int u = (w * 8 + c) * 64 + lane;
            int n = u >> 3;
            int kbs = (u & 7) ^ (n & 7);
            load_lds16(Ht + n * NN + kbs * 8 + k0, &Bs[(w * 8 + c) * 512]);
        }
        // ---- A: convert adj regs -> bf16 {0,1}, one contiguous b128/thread
        {
            unsigned d0 = (av[0] > 0 ? 0x3F80u : 0u) | (av[1] > 0 ? 0x3F800000u : 0u);
            unsigned d1 = (av[2] > 0 ? 0x3F80u : 0u) | (av[3] > 0 ? 0x3F800000u : 0u);
            unsigned d2 = (av[4] > 0 ? 0x3F80u : 0u) | (av[5] > 0 ? 0x3F800000u : 0u);
            unsigned d3 = (av[6] > 0 ? 0x3F80u : 0u) | (av[7] > 0 ? 0x3F800000u : 0u);
            int4 t;
            t.x = (int)d0; t.y = (int)d1; t.z = (int)d2; t.w = (int)d3;
            *(int4*)&As[lane * PADK + w * 8] = t;
        }
        __syncthreads();                      // drain: LDS ready
        // ---- compute: 2 K-substeps x 4x4 frags
#pragma unroll
        for (int ks = 0; ks < 2; ++ks) {
            short8 af[4];
#pragma unroll
            for (int r = 0; r < 4; ++r)
                af[r] = *(const short8*)&As[(r * 16 + m) * PADK + ks * 32 + q * 8];
#pragma unroll
            for (int c = 0; c < 4; ++c) {
                int row = wn + c * 16 + m;
                int kbs = (ks * 4 + q) ^ (m & 7);   // row&7 == m&7
                short8 bfr = *(const short8*)&Bs[row * 64 + kbs * 8];
#pragma unroll
                for (int r = 0; r < 4; ++r)
                    acc[r][c] = __builtin_amdgcn_mfma_f32_16x16x32_bf16(af[r], bfr, acc[r][c], 0, 0, 0);
            }
        }
    }

    // ---- fused epilogue: s2 partial = sum_o nbr*a2, m-lane reduce, atomic
    const bool isbf = (*flagp != 0u);
    const int btA = wn >> 5;                  // = 2*w
#pragma unroll
    for (int r = 0; r < 4; ++r) {
#pragma unroll
        for (int e = 0; e < 4; ++e) {
            int gi = i0 + r * 16 + q * 4 + e;
            float a2m, a2m16;
            if (isbf) {
                const unsigned short* ab = (const unsigned short*)a_raw;
                a2m   = bf2f(ab[(size_t)(FOUT + m) * NN + gi]);
                a2m16 = bf2f(ab[(size_t)(FOUT + 16 + m) * NN + gi]);
            } else {
                const float* afp = (const float*)a_raw;
                a2m   = afp[(size_t)(FOUT + m) * NN + gi];
                a2m16 = afp[(size_t)(FOUT + 16 + m) * NN + gi];
            }
            float sA = acc[r][0][e] * a2m + acc[r][1][e] * a2m16;
            float sB = acc[r][2][e] * a2m + acc[r][3][e] * a2m16;
            sA += __shfl_xor(sA, 1); sA += __shfl_xor(sA, 2);
            sA += __shfl_xor(sA, 4); sA += __shfl_xor(sA, 8);
            sB += __shfl_xor(sB, 1); sB += __shfl_xor(sB, 2);
            sB += __shfl_xor(sB, 4); sB += __shfl_xor(sB, 8);
            if (m == 0) {
                atomicAdd(&s2[(size_t)btA * NN + gi], sA);
                atomicAdd(&s2[(size_t)(btA + 1) * NN + gi], sB);
            }
        }
    }
}

// ---------------------------------------------------------------------------
// K3: s = s2 + sum_o h*a1 ; out = relu(s * sumh[bt,:])
// ---------------------------------------------------------------------------
__launch_bounds__(256)
__global__ void k3_out(const unsigned short* __restrict__ Ht, const float* __restrict__ s2,
                       const float* __restrict__ sumh, const void* __restrict__ a_raw,
                       void* __restrict__ out_raw, const unsigned* __restrict__ flagp) {
    const int i = blockIdx.x * 256 + threadIdx.x;
    const int bt = blockIdx.y;
    const bool isbf = (*flagp != 0u);

    float s = s2[(size_t)bt * NN + i];
    if (isbf) {
        const unsigned short* ab = (const unsigned short*)a_raw;
#pragma unroll
        for (int o = 0; o < 32; ++o) {
            float h = bf2f(Ht[(size_t)(bt * FOUT + o) * NN + i]);
            s += h * bf2f(ab[(size_t)o * NN + i]);
        }
    } else {
        const float* afp = (const float*)a_raw;
#pragma unroll
        for (int o = 0; o < 32; ++o) {
            float h = bf2f(Ht[(size_t)(bt * FOUT + o) * NN + i]);
            s += h * afp[(size_t)o * NN + i];
        }
    }

    float ov[32];
#pragma unroll
    for (int o = 0; o < 32; ++o) ov[o] = fmaxf(s * sumh[bt * FOUT + o], 0.f);

    size_t ob = ((size_t)bt * NN + i) * FOUT;
    if (isbf) {
        unsigned short* o16 = (unsigned short*)out_raw + ob;
#pragma unroll
        for (int c = 0; c < 8; ++c) {
            ushort4 p;
            p.x = f2bf(ov[c * 4 + 0]); p.y = f2bf(ov[c * 4 + 1]);
            p.z = f2bf(ov[c * 4 + 2]); p.w = f2bf(ov[c * 4 + 3]);
            *(ushort4*)(o16 + c * 4) = p;
        }
    } else {
        float* of = (float*)out_raw + ob;
#pragma unroll
        for (int c = 0; c < 8; ++c) {
            float4 v;
            v.x = ov[c * 4 + 0]; v.y = ov[c * 4 + 1]; v.z = ov[c * 4 + 2]; v.w = ov[c * 4 + 3];
            *(float4*)(of + c * 4) = v;
        }
    }
}

// ---------------------------------------------------------------------------
extern "C" void kernel_launch(void* const* d_in, const int* in_sizes, int n_in,
                              void* d_out, int out_size, void* d_ws, size_t ws_size,
                              hipStream_t stream) {
    const void* inp = d_in[0];
    const int* adj = (const int*)d_in[1];
    const void* W = d_in[2];
    const void* a = d_in[3];

    char* ws = (char*)d_ws;
    unsigned short* Ht = (unsigned short*)ws;                    // 8 MB
    unsigned* flag = (unsigned*)(ws + 8388608);                  // 4 B
    float* s2 = (float*)(ws + 8388608 + 4096);                   // 512 KB (16B aligned)
    float* sumh = (float*)(ws + 8388608 + 4096 + 524288);        // 2 KB

    sniff_dtype<<<1, 64, 0, stream>>>((const unsigned*)W, flag, sumh);
    k1<<<1152, 256, 0, stream>>>(inp, W, Ht, sumh, (float4*)s2, flag);
    k2_fused<<<512, 512, 0, stream>>>(adj, Ht, a, s2, flag);
    k3_out<<<dim3(NN / 256, BT), 256, 0, stream>>>(Ht, s2, sumh, a, d_out, flag);
}

// Round 3
// 482.725 us; speedup vs baseline: 1.0108x; 1.0108x over previous
//
#include <hip/hip_runtime.h>

#define BT 16
#define NN 8192
#define FIN 128
#define FOUT 32
#define NB 512       // BT*FOUT
#define SPLITK 4
#define KSPAN (NN / SPLITK)   // 2048
#define BKK 64
#define PADK 72      // As row stride: 144 B -> conflict-free in 8-lane groups

typedef __attribute__((ext_vector_type(8))) short short8;
typedef __attribute__((ext_vector_type(4))) float float4v;

__device__ __forceinline__ float bf2f(unsigned short u) {
    unsigned v = ((unsigned)u) << 16;
    float f;
    __builtin_memcpy(&f, &v, 4);
    return f;
}
__device__ __forceinline__ unsigned short f2bf(float f) {
    unsigned u;
    __builtin_memcpy(&u, &f, 4);
    u += 0x7FFFu + ((u >> 16) & 1u);   // RNE
    return (unsigned short)(u >> 16);
}

// async global->LDS, 16 B per lane; LDS dest = wave-uniform base + lane*16
__device__ __forceinline__ void load_lds16(const unsigned short* g, unsigned short* l) {
    __builtin_amdgcn_global_load_lds((const __attribute__((address_space(1))) void*)g,
                                     (__attribute__((address_space(3))) void*)l, 16, 0, 0);
}

// ---------------------------------------------------------------------------
// Sniff bf16-vs-fp32 (proven R1/R2) + zero sumh[512].
// ---------------------------------------------------------------------------
__global__ void sniff_dtype(const unsigned* __restrict__ Wraw, unsigned* __restrict__ flag,
                            float* __restrict__ sumh) {
    int lane = threadIdx.x;
    unsigned u = Wraw[lane];
    float f = bf2f((unsigned short)(u & 0xFFFFu));
    float af = fabsf(f);
    bool plaus = (af > 1e-5f) && (af < 1e3f);
    unsigned long long msk = __ballot(plaus);
    if (lane == 0) flag[0] = (__popcll(msk) >= 32) ? 1u : 0u;
#pragma unroll
    for (int r = 0; r < 8; ++r) sumh[lane + 64 * r] = 0.f;
}

// ---------------------------------------------------------------------------
// K1: [0,128) zero s2 | [128,1152) h = inp @ W  (+ per-bt column sums of h)
// ---------------------------------------------------------------------------
__launch_bounds__(256)
__global__ void k1(const void* __restrict__ inp_raw, const void* __restrict__ W_raw,
                   unsigned short* __restrict__ Ht, float* __restrict__ sumh,
                   float4* __restrict__ s2v, const unsigned* __restrict__ flagp) {
    __shared__ __align__(16) unsigned short Wt[32 * 136];
    int bid = blockIdx.x;
    const int tid = threadIdx.x;

    if (bid < 128) {                 // ---- zero s2 (131072 floats = 32768 float4)
        float4 z; z.x = z.y = z.z = z.w = 0.f;
        s2v[bid * 256 + tid] = z;
        return;
    }
    bid -= 128;                      // ---- h-part (R2 k1 body, proven)
    const int bt = bid >> 6;
    const int j0 = (bid & 63) * 128;
    const bool isbf = (*flagp != 0u);

    if (isbf) {
        const unsigned short* Wb = (const unsigned short*)W_raw;
#pragma unroll
        for (int r = 0; r < 16; ++r) {
            int idx = tid + 256 * r, i = idx >> 5, o = idx & 31;
            Wt[o * 136 + i] = Wb[idx];
        }
    } else {
        const float* Wf = (const float*)W_raw;
#pragma unroll
        for (int r = 0; r < 16; ++r) {
            int idx = tid + 256 * r, i = idx >> 5, o = idx & 31;
            Wt[o * 136 + i] = f2bf(Wf[idx]);
        }
    }
    __syncthreads();

    const int lane = tid & 63, w = tid >> 6;
    const int m = lane & 15, q = lane >> 4;
    const int mt = (w & 1) * 16;
    const int nt = (w >> 1) * 64;

    float4v acc[4];
#pragma unroll
    for (int c = 0; c < 4; ++c) { float4v z = {0.f, 0.f, 0.f, 0.f}; acc[c] = z; }

#pragma unroll
    for (int kstep = 0; kstep < 4; ++kstep) {
        short8 af = *(const short8*)&Wt[(mt + m) * 136 + kstep * 32 + q * 8];
#pragma unroll
        for (int c = 0; c < 4; ++c) {
            int j = j0 + nt + c * 16 + m;
            short8 bfrag;
            if (isbf) {
                bfrag = *(const short8*)((const unsigned short*)inp_raw +
                        ((size_t)bt * NN + j) * FIN + kstep * 32 + q * 8);
            } else {
                const float* fp = (const float*)inp_raw + ((size_t)bt * NN + j) * FIN + kstep * 32 + q * 8;
                float4 f0 = *(const float4*)fp;
                float4 f1 = *(const float4*)(fp + 4);
                union { unsigned short u[8]; short8 v; } t;
                t.u[0] = f2bf(f0.x); t.u[1] = f2bf(f0.y); t.u[2] = f2bf(f0.z); t.u[3] = f2bf(f0.w);
                t.u[4] = f2bf(f1.x); t.u[5] = f2bf(f1.y); t.u[6] = f2bf(f1.z); t.u[7] = f2bf(f1.w);
                bfrag = t.v;
            }
            acc[c] = __builtin_amdgcn_mfma_f32_16x16x32_bf16(af, bfrag, acc[c], 0, 0, 0);
        }
    }

#pragma unroll
    for (int c = 0; c < 4; ++c) {
#pragma unroll
        for (int e = 0; e < 4; ++e) {
            int o = mt + q * 4 + e;
            int j = j0 + nt + c * 16 + m;
            Ht[(size_t)(bt * FOUT + o) * NN + j] = f2bf(acc[c][e]);
        }
    }
#pragma unroll
    for (int e = 0; e < 4; ++e) {
        float s = acc[0][e] + acc[1][e] + acc[2][e] + acc[3][e];
        s += __shfl_xor(s, 1); s += __shfl_xor(s, 2);
        s += __shfl_xor(s, 4); s += __shfl_xor(s, 8);
        if (m == 0) atomicAdd(&sumh[bt * FOUT + mt + q * 4 + e], s);
    }
}

// ---------------------------------------------------------------------------
// K2 fused: s2[bt][i] += sum_o a2[i,o] * (sum_k (adj[k][i]>0) * Ht[bt*32+o][k])
// Counted-vmcnt pipeline (T4): raw s_barriers, adj prefetch stays IN FLIGHT
// across barrier-2 via asm s_waitcnt vmcnt(8) (drains only the 8 gload_lds).
// vmcnt bookkeeping invariant: loop entry = 8 adj outstanding; +8 gload = 16;
// convert auto-wait vmcnt(8) -> 8; +8 adj-next = 16; asm vmcnt(8) -> 8.
// Last iteration issues dummy prefetch (kept alive vs DCE) to preserve counts.
// ---------------------------------------------------------------------------
__launch_bounds__(512, 4)
__global__ void k2_fused(const int* __restrict__ adj, const unsigned short* __restrict__ Ht,
                         const void* __restrict__ a_raw, float* __restrict__ s2,
                         const unsigned* __restrict__ flagp) {
    __shared__ __align__(16) unsigned short As[64 * PADK];   // 9.2 KB
    __shared__ __align__(16) unsigned short Bs[512 * 64];    // 64 KB
    const int tid = threadIdx.x;
    const int lane = tid & 63;
    const int w = tid >> 6;              // wave 0..7, owns n in [w*64, w*64+64)
    const int m = lane & 15, q = lane >> 4;
    const int wn = w * 64;

    // XCD-aware decomposition: bid&7 ~ XCD; 2 XCDs per z-slice -> each XCD's
    // 2 MB Ht k-slice stays resident in its private L2.
    const int bid = blockIdx.x;
    const int xcd = bid & 7;
    const int z = xcd >> 1;                          // 0..3
    const int ib = (bid >> 3) | ((xcd & 1) << 6);    // 0..127 (bijective)
    const int i0 = ib * 64;
    const int zbase = z * KSPAN;

    // per-lane DMA source offsets (halfword units) for the 8 calls/wave:
    // unit u covers LDS slot (n = u>>3, kb = u&7); source octet kb ^ (n&7).
    int boff[8];
#pragma unroll
    for (int c = 0; c < 8; ++c) {
        int u = (w * 8 + c) * 64 + lane;
        int n = u >> 3;
        int kbs = (u & 7) ^ (n & 7);
        boff[c] = n * NN + kbs * 8;
    }

    // A staging: this thread covers column i = i0+lane, k-octet kh = w.
    const int* gcol = adj + (zbase + w * 8) * NN + i0 + lane;

    float4v acc[4][4];
#pragma unroll
    for (int r = 0; r < 4; ++r)
#pragma unroll
        for (int c = 0; c < 4; ++c) { float4v zz = {0.f, 0.f, 0.f, 0.f}; acc[r][c] = zz; }

    // prologue: issue adj(0) -> loop-entry invariant: 8 outstanding
    int av[8];
#pragma unroll
    for (int kk = 0; kk < 8; ++kk)
        av[kk] = gcol[kk * NN];

    for (int ks0 = 0; ks0 < KSPAN; ks0 += BKK) {
        const int k0 = zbase + ks0;
        __builtin_amdgcn_s_barrier();            // barrier-1: plain, no drain
        __builtin_amdgcn_sched_barrier(0);
        // ---- B: 8 DMA calls/wave (outstanding: 8 adj + 8 gload)
#pragma unroll
        for (int c = 0; c < 8; ++c)
            load_lds16(Ht + boff[c] + k0, &Bs[(w * 8 + c) * 512]);
        // ---- A: convert adj regs (compiler auto-emits exact vmcnt(8) here)
        unsigned d0 = (av[0] > 0 ? 0x3F80u : 0u) | (av[1] > 0 ? 0x3F800000u : 0u);
        unsigned d1 = (av[2] > 0 ? 0x3F80u : 0u) | (av[3] > 0 ? 0x3F800000u : 0u);
        unsigned d2 = (av[4] > 0 ? 0x3F80u : 0u) | (av[5] > 0 ? 0x3F800000u : 0u);
        unsigned d3 = (av[6] > 0 ? 0x3F80u : 0u) | (av[7] > 0 ? 0x3F800000u : 0u);
        // ---- prefetch adj for next step (dummy re-load of step 0 on the last
        // iteration to keep the vmcnt invariant; values then unused)
        const int ksn = (ks0 + BKK < KSPAN) ? ks0 + BKK : 0;
#pragma unroll
        for (int kk = 0; kk < 8; ++kk)
            av[kk] = gcol[(ksn + kk) * NN];
        // ---- As write
        {
            int4 t;
            t.x = (int)d0; t.y = (int)d1; t.z = (int)d2; t.w = (int)d3;
            *(int4*)&As[lane * PADK + w * 8] = t;
        }
        // drain ONLY the gloads (oldest 8 of 16); adj prefetch stays in flight
        asm volatile("s_waitcnt vmcnt(8) lgkmcnt(0)" ::: "memory");
        __builtin_amdgcn_sched_barrier(0);
        __builtin_amdgcn_s_barrier();            // barrier-2
        __builtin_amdgcn_sched_barrier(0);
        // ---- compute: 2 K-substeps x 4x4 frags
#pragma unroll
        for (int ks = 0; ks < 2; ++ks) {
            short8 af[4];
#pragma unroll
            for (int r = 0; r < 4; ++r)
                af[r] = *(const short8*)&As[(r * 16 + m) * PADK + ks * 32 + q * 8];
#pragma unroll
            for (int c = 0; c < 4; ++c) {
                int row = wn + c * 16 + m;
                int kbs = (ks * 4 + q) ^ (m & 7);   // row&7 == m&7
                short8 bfr = *(const short8*)&Bs[row * 64 + kbs * 8];
#pragma unroll
                for (int r = 0; r < 4; ++r)
                    acc[r][c] = __builtin_amdgcn_mfma_f32_16x16x32_bf16(af[r], bfr, acc[r][c], 0, 0, 0);
            }
        }
    }
    // keep the final dummy prefetch alive so DCE can't break the vmcnt counts
    asm volatile("" :: "v"(av[0]), "v"(av[1]), "v"(av[2]), "v"(av[3]),
                       "v"(av[4]), "v"(av[5]), "v"(av[6]), "v"(av[7]));

    // ---- fused epilogue: s2 partial = sum_o nbr*a2, m-lane reduce, atomic
    const bool isbf = (*flagp != 0u);
    const int btA = wn >> 5;                  // = 2*w
#pragma unroll
    for (int r = 0; r < 4; ++r) {
#pragma unroll
        for (int e = 0; e < 4; ++e) {
            int gi = i0 + r * 16 + q * 4 + e;
            float a2m, a2m16;
            if (isbf) {
                const unsigned short* ab = (const unsigned short*)a_raw;
                a2m   = bf2f(ab[(size_t)(FOUT + m) * NN + gi]);
                a2m16 = bf2f(ab[(size_t)(FOUT + 16 + m) * NN + gi]);
            } else {
                const float* afp = (const float*)a_raw;
                a2m   = afp[(size_t)(FOUT + m) * NN + gi];
                a2m16 = afp[(size_t)(FOUT + 16 + m) * NN + gi];
            }
            float sA = acc[r][0][e] * a2m + acc[r][1][e] * a2m16;
            float sB = acc[r][2][e] * a2m + acc[r][3][e] * a2m16;
            sA += __shfl_xor(sA, 1); sA += __shfl_xor(sA, 2);
            sA += __shfl_xor(sA, 4); sA += __shfl_xor(sA, 8);
            sB += __shfl_xor(sB, 1); sB += __shfl_xor(sB, 2);
            sB += __shfl_xor(sB, 4); sB += __shfl_xor(sB, 8);
            if (m == 0) {
                atomicAdd(&s2[(size_t)btA * NN + gi], sA);
                atomicAdd(&s2[(size_t)(btA + 1) * NN + gi], sB);
            }
        }
    }
}

// ---------------------------------------------------------------------------
// K3: s = s2 + sum_o h*a1 ; out = relu(s * sumh[bt,:])
// ---------------------------------------------------------------------------
__launch_bounds__(256)
__global__ void k3_out(const unsigned short* __restrict__ Ht, const float* __restrict__ s2,
                       const float* __restrict__ sumh, const void* __restrict__ a_raw,
                       void* __restrict__ out_raw, const unsigned* __restrict__ flagp) {
    const int i = blockIdx.x * 256 + threadIdx.x;
    const int bt = blockIdx.y;
    const bool isbf = (*flagp != 0u);

    float s = s2[(size_t)bt * NN + i];
    if (isbf) {
        const unsigned short* ab = (const unsigned short*)a_raw;
#pragma unroll
        for (int o = 0; o < 32; ++o) {
            float h = bf2f(Ht[(size_t)(bt * FOUT + o) * NN + i]);
            s += h * bf2f(ab[(size_t)o * NN + i]);
        }
    } else {
        const float* afp = (const float*)a_raw;
#pragma unroll
        for (int o = 0; o < 32; ++o) {
            float h = bf2f(Ht[(size_t)(bt * FOUT + o) * NN + i]);
            s += h * afp[(size_t)o * NN + i];
        }
    }

    float ov[32];
#pragma unroll
    for (int o = 0; o < 32; ++o) ov[o] = fmaxf(s * sumh[bt * FOUT + o], 0.f);

    size_t ob = ((size_t)bt * NN + i) * FOUT;
    if (isbf) {
        unsigned short* o16 = (unsigned short*)out_raw + ob;
#pragma unroll
        for (int c = 0; c < 8; ++c) {
            ushort4 p;
            p.x = f2bf(ov[c * 4 + 0]); p.y = f2bf(ov[c * 4 + 1]);
            p.z = f2bf(ov[c * 4 + 2]); p.w = f2bf(ov[c * 4 + 3]);
            *(ushort4*)(o16 + c * 4) = p;
        }
    } else {
        float* of = (float*)out_raw + ob;
#pragma unroll
        for (int c = 0; c < 8; ++c) {
            float4 v;
            v.x = ov[c * 4 + 0]; v.y = ov[c * 4 + 1]; v.z = ov[c * 4 + 2]; v.w = ov[c * 4 + 3];
            *(float4*)(of + c * 4) = v;
        }
    }
}

// ---------------------------------------------------------------------------
extern "C" void kernel_launch(void* const* d_in, const int* in_sizes, int n_in,
                              void* d_out, int out_size, void* d_ws, size_t ws_size,
                              hipStream_t stream) {
    const void* inp = d_in[0];
    const int* adj = (const int*)d_in[1];
    const void* W = d_in[2];
    const void* a = d_in[3];

    char* ws = (char*)d_ws;
    unsigned short* Ht = (unsigned short*)ws;                    // 8 MB
    unsigned* flag = (unsigned*)(ws + 8388608);                  // 4 B
    float* s2 = (float*)(ws + 8388608 + 4096);                   // 512 KB (16B aligned)
    float* sumh = (float*)(ws + 8388608 + 4096 + 524288);        // 2 KB

    sniff_dtype<<<1, 64, 0, stream>>>((const unsigned*)W, flag, sumh);
    k1<<<1152, 256, 0, stream>>>(inp, W, Ht, sumh, (float4*)s2, flag);
    k2_fused<<<512, 512, 0, stream>>>(adj, Ht, a, s2, flag);
    k3_out<<<dim3(NN / 256, BT), 256, 0, stream>>>(Ht, s2, sumh, a, d_out, flag);
}